// Round 8
// baseline (195.545 us; speedup 1.0000x reference)
//
#include <hip/hip_runtime.h>
#include <hip/hip_bf16.h>
#include <stdint.h>

#define HID 256
#define NTOK 8192
#define NS 8
#define SLICE (NTOK / NS)        // 1024 tokens per slice
#define CHUNK 32
#define NCH (SLICE / CHUNK)      // 32 chunks per slice

typedef unsigned short u16;
typedef unsigned int u32;
typedef __bf16 bf16x8 __attribute__((ext_vector_type(8)));
typedef float f32x16 __attribute__((ext_vector_type(16)));
typedef __fp16 h16x2 __attribute__((ext_vector_type(2)));

// D-layout row index for 32x32 MFMA: row = (r&3) + 8*(r>>2) + 4*h
#define TAU(r, h) (((r) & 3) + 8 * ((r) >> 2) + 4 * (h))

__device__ __forceinline__ u16 f2bf(float f) {
  u32 u = __float_as_uint(f);
  return (u16)((u + 0x7FFFu + ((u >> 16) & 1u)) >> 16);
}

__device__ __forceinline__ u32 cvtpk_bf16(float a, float b) {
  u32 r;
  asm("v_cvt_pk_bf16_f32 %0, %1, %2" : "=v"(r) : "v"(a), "v"(b));
  return r;
}

__device__ __forceinline__ u32 cvtpk_f16(float a, float b) {
  union { h16x2 h; u32 u; } cv;
  cv.h = __builtin_amdgcn_cvt_pkrtz(a, b);
  return cv.u;
}

// ---------------------------------------------------------------------------
// W fp32 -> bf16 (3 x 256x256)   [R3 verbatim — validated]
// ---------------------------------------------------------------------------
__global__ void wcvt_kernel(const float* __restrict__ Wq, const float* __restrict__ Wk,
                            const float* __restrict__ Wv, u16* __restrict__ out) {
  int idx = blockIdx.x * 256 + threadIdx.x;
  int mat = idx >> 14;
  int off = (idx & 16383) << 2;
  const float* src = mat == 0 ? Wq : (mat == 1 ? Wk : Wv);
  float4 v = *reinterpret_cast<const float4*>(src + off);
  ushort4 o;
  o.x = f2bf(v.x); o.y = f2bf(v.y); o.z = f2bf(v.z); o.w = f2bf(v.w);
  *reinterpret_cast<ushort4*>(out + mat * 65536 + off) = o;
}

// ---------------------------------------------------------------------------
// Projection [R3 structure; M/N-split for 2x grid]: 64 rows/block, wave-pairs
// split the 256 output cols (wrow = wid&1 picks row half, wcol = wid>>1 picks
// col half). q,k row-major [8192][256], v -> [256][8192]. grid 384 = 3*128.
// ---------------------------------------------------------------------------
__global__ __launch_bounds__(256, 2) void proj_kernel(
    const float* __restrict__ Xq, const float* __restrict__ Xk, const float* __restrict__ Xv,
    const u16* __restrict__ wcvt,
    const float* __restrict__ Bq, const float* __restrict__ Bk, const float* __restrict__ Bv,
    u16* __restrict__ oq, u16* __restrict__ ok, u16* __restrict__ ovt)
{
  __shared__ __attribute__((aligned(16))) unsigned char smem[32768 + 4 * 4352];
  u16* wbuf0 = (u16*)smem;
  u16* wbuf1 = (u16*)(smem + 16384);
  float* scratch = (float*)(smem + 32768 + (threadIdx.x >> 6) * 4352);

  const int tid = threadIdx.x, bid = blockIdx.x;
  const int sel = bid >> 7;             // 0:q 1:k 2:v   (128 blocks each)
  const int m0 = (bid & 127) << 6;      // 64 rows/block
  const int wid = tid >> 6, l = tid & 63;
  const int l31 = l & 31, lh = l >> 5;
  const int wrow = wid & 1;             // row half within block
  const int wcol = wid >> 1;            // col half (4 nt-blocks each)

  const float* X = sel == 0 ? Xq : (sel == 1 ? Xk : Xv);
  const u16* W = wcvt + sel * 65536;
  const float* B = sel == 0 ? Bq : (sel == 1 ? Bk : Bv);
  const int mrow = m0 + wrow * 32 + l31;

  f32x16 acc[4];
#pragma unroll
  for (int nt = 0; nt < 4; ++nt) acc[nt] = (f32x16)0.f;

  auto stageW = [&](int kc, u16* buf) {   // [4 hid-octet][256 n] — unchanged
#pragma unroll
    for (int ii = 0; ii < 4; ++ii) {
      int u = (wid * 4 + ii) * 64 + l;
      int ol = u >> 8, n = u & 255;
      const u16* g = W + n * HID + kc * 32 + ol * 8;
      __builtin_amdgcn_global_load_lds((const __attribute__((address_space(1))) u32*)g,
                                       (__attribute__((address_space(3))) u32*)(buf + (size_t)u * 8),
                                       16, 0, 0);
    }
  };

  stageW(0, wbuf0);
  __syncthreads();
  for (int kc = 0; kc < 8; ++kc) {
    u16* cur = (kc & 1) ? wbuf1 : wbuf0;
    if (kc < 7) stageW(kc + 1, (kc & 1) ? wbuf0 : wbuf1);
#pragma unroll
    for (int k2 = 0; k2 < 2; ++k2) {
      int ks = kc * 2 + k2;
      float4 a0 = *reinterpret_cast<const float4*>(X + (size_t)mrow * HID + ks * 16 + lh * 8);
      float4 a1 = *reinterpret_cast<const float4*>(X + (size_t)mrow * HID + ks * 16 + lh * 8 + 4);
      union { u16 u[8]; bf16x8 v; } au;
      au.u[0] = f2bf(a0.x); au.u[1] = f2bf(a0.y); au.u[2] = f2bf(a0.z); au.u[3] = f2bf(a0.w);
      au.u[4] = f2bf(a1.x); au.u[5] = f2bf(a1.y); au.u[6] = f2bf(a1.z); au.u[7] = f2bf(a1.w);
#pragma unroll
      for (int nt = 0; nt < 4; ++nt) {
        int unit = (k2 * 2 + lh) * 256 + (wcol * 4 + nt) * 32 + l31;
        bf16x8 b = *reinterpret_cast<bf16x8*>(cur + (size_t)unit * 8);
        acc[nt] = __builtin_amdgcn_mfma_f32_32x32x16_bf16(au.v, b, acc[nt], 0, 0, 0);
      }
    }
    __syncthreads();
  }

#pragma unroll
  for (int nt = 0; nt < 4; ++nt) {
    const int colblk = wcol * 4 + nt;
    float bv = B[colblk * 32 + l31];
#pragma unroll
    for (int r = 0; r < 16; ++r)
      scratch[TAU(r, lh) * 33 + l31] = acc[nt][r] + bv;   // [m_local][n_local]
    if (sel < 2) {
      u16* o = sel == 0 ? oq : ok;
      u16 tmp[16];
#pragma unroll
      for (int c = 0; c < 16; ++c) tmp[c] = f2bf(scratch[l31 * 33 + lh * 16 + c]);
      u16* dst = o + (size_t)mrow * HID + colblk * 32 + lh * 16;
      *reinterpret_cast<uint4*>(dst) = *reinterpret_cast<uint4*>(&tmp[0]);
      *reinterpret_cast<uint4*>(dst + 8) = *reinterpret_cast<uint4*>(&tmp[8]);
    } else {
      u16 tmp[16];
#pragma unroll
      for (int c = 0; c < 16; ++c) tmp[c] = f2bf(scratch[(lh * 16 + c) * 33 + l31]);
      u16* dst = ovt + (size_t)(colblk * 32 + l31) * NTOK + m0 + wrow * 32 + lh * 16;
      *reinterpret_cast<uint4*>(dst) = *reinterpret_cast<uint4*>(&tmp[0]);
      *reinterpret_cast<uint4*>(dst + 8) = *reinterpret_cast<uint4*>(&tmp[8]);
    }
  }
}

// ---------------------------------------------------------------------------
// Fused sigmoid attention [R3-exact loop structure]; 4 waves / 128 q-rows per
// block -> grid 512 = 64 qt * 8 slices = 2 blocks/CU (two barrier domains).
// ---------------------------------------------------------------------------
__global__ __launch_bounds__(256, 2) void attn_kernel(
    const u16* __restrict__ qw, const u16* __restrict__ kw,
    const u16* __restrict__ vtw, u16* __restrict__ partial)
{
  __shared__ __attribute__((aligned(16))) unsigned char smem[65536];
  u16* kb0 = (u16*)smem;            u16* kb1 = (u16*)(smem + 16384);
  u16* vb0 = (u16*)(smem + 32768);  u16* vb1 = (u16*)(smem + 49152);

  const int tid = threadIdx.x, bid = blockIdx.x;
  const int slice = bid & 7, qt = bid >> 3;      // qt in [0,64)
  const int q0 = qt * 128;
  const int tokbase = slice * SLICE;
  const int wq = tid >> 6, l = tid & 63;         // wq in [0,4)
  const int l31 = l & 31, lh = l >> 5;
  const int qrow = q0 + wq * 32 + l31;

  // Q B-fragments from row-major q  [R3 validated]
  bf16x8 qB[16];
#pragma unroll
  for (int ks = 0; ks < 16; ++ks)
    qB[ks] = *reinterpret_cast<const bf16x8*>(qw + (size_t)qrow * HID + ks * 16 + lh * 8);

  auto stageK = [&](int c, u16* buf) {   // [32 hid-octet][32 tok]; 4 waves x 4 units
    int tok0 = tokbase + c * CHUNK;
#pragma unroll
    for (int ii = 0; ii < 4; ++ii) {
      int u = (wq * 4 + ii) * 64 + l;
      int o = u >> 5, t = u & 31;
      const u16* g = kw + (size_t)(tok0 + t) * HID + o * 8;
      __builtin_amdgcn_global_load_lds((const __attribute__((address_space(1))) u32*)g,
                                       (__attribute__((address_space(3))) u32*)(buf + (size_t)u * 8),
                                       16, 0, 0);
    }
  };
  auto stageV = [&](int c, u16* buf) {   // [4 tok-octet][256 d]; 4 waves x 4 units
    int tok0 = tokbase + c * CHUNK;
#pragma unroll
    for (int ii = 0; ii < 4; ++ii) {
      int u = (wq * 4 + ii) * 64 + l;
      int j = u >> 8, d = u & 255;
      const u16* g = vtw + (size_t)d * NTOK + tok0 + j * 8;
      __builtin_amdgcn_global_load_lds((const __attribute__((address_space(1))) u32*)g,
                                       (__attribute__((address_space(3))) u32*)(buf + (size_t)u * 8),
                                       16, 0, 0);
    }
  };

  f32x16 oacc[8];
#pragma unroll
  for (int dt = 0; dt < 8; ++dt) oacc[dt] = (f32x16)0.f;

  stageK(0, kb0);
  stageV(0, vb0);
  __syncthreads();

  for (int c = 0; c < NCH; ++c) {
    u16* kc_ = (c & 1) ? kb1 : kb0;
    u16* vc_ = (c & 1) ? vb1 : vb0;
    if (c + 1 < NCH) {
      stageK(c + 1, (c & 1) ? kb0 : kb1);
      stageV(c + 1, (c & 1) ? vb0 : vb1);
    }

    // S^T = K * Q^T
    f32x16 sacc = (f32x16)0.f;
#pragma unroll
    for (int ks = 0; ks < 16; ++ks) {
      bf16x8 kf = *reinterpret_cast<bf16x8*>(kc_ + (size_t)((ks * 2 + lh) * 32 + l31) * 8);
      sacc = __builtin_amdgcn_mfma_f32_32x32x16_bf16(kf, qB[ks], sacc, 0, 0, 0);
    }

    // sigmoid
    float p[16];
#pragma unroll
    for (int r = 0; r < 16; ++r) {
      float e = __expf(-sacc[r]);
      p[r] = __builtin_amdgcn_rcpf(1.0f + e);
    }

    // pack P^T into PV B-fragments
    u32 w0[4], w1[4];
    {
      u32 x0 = cvtpk_bf16(p[0], p[1]),  y0 = cvtpk_bf16(p[4], p[5]);
      asm volatile("v_permlane32_swap_b32 %0, %1" : "+v"(x0), "+v"(y0));
      u32 x1 = cvtpk_bf16(p[2], p[3]),  y1 = cvtpk_bf16(p[6], p[7]);
      asm volatile("v_permlane32_swap_b32 %0, %1" : "+v"(x1), "+v"(y1));
      w0[0] = x0; w0[1] = x1; w0[2] = y0; w0[3] = y1;
      u32 x2 = cvtpk_bf16(p[8], p[9]),  y2 = cvtpk_bf16(p[12], p[13]);
      asm volatile("v_permlane32_swap_b32 %0, %1" : "+v"(x2), "+v"(y2));
      u32 x3 = cvtpk_bf16(p[10], p[11]), y3 = cvtpk_bf16(p[14], p[15]);
      asm volatile("v_permlane32_swap_b32 %0, %1" : "+v"(x3), "+v"(y3));
      w1[0] = x2; w1[1] = x3; w1[2] = y2; w1[3] = y3;
    }

    // O^T += V^T * P^T
#pragma unroll
    for (int kp = 0; kp < 2; ++kp) {
      union { u32 u[4]; bf16x8 v; } pb;
      pb.u[0] = kp ? w1[0] : w0[0]; pb.u[1] = kp ? w1[1] : w0[1];
      pb.u[2] = kp ? w1[2] : w0[2]; pb.u[3] = kp ? w1[3] : w0[3];
#pragma unroll
      for (int dt = 0; dt < 8; ++dt) {
        bf16x8 vf = *reinterpret_cast<bf16x8*>(vc_ + (size_t)((kp * 2 + lh) * 256 + dt * 32 + l31) * 8);
        oacc[dt] = __builtin_amdgcn_mfma_f32_32x32x16_bf16(vf, pb.v, oacc[dt], 0, 0, 0);
      }
    }

    __syncthreads();   // drains this chunk's prefetch; frees buffers
  }

  // epilogue [R3 verbatim]: per-wave stride-33 transpose, fp16 partial
  float* scratch = (float*)(smem + wq * 4352);
  u16* part = partial + (size_t)slice * NTOK * HID;
#pragma unroll
  for (int dt = 0; dt < 8; ++dt) {
#pragma unroll
    for (int r = 0; r < 16; ++r)
      scratch[TAU(r, lh) * 33 + l31] = oacc[dt][r];      // [d_local][q_local]
    u32 pk[8];
#pragma unroll
    for (int c2 = 0; c2 < 8; ++c2) {
      float f0 = scratch[(lh * 16 + 2 * c2) * 33 + l31];
      float f1 = scratch[(lh * 16 + 2 * c2 + 1) * 33 + l31];
      pk[c2] = cvtpk_f16(f0, f1);
    }
    u16* dst = part + (size_t)qrow * HID + dt * 32 + lh * 16;
    *reinterpret_cast<uint4*>(dst) = *reinterpret_cast<uint4*>(&pk[0]);
    *reinterpret_cast<uint4*>(dst + 8) = *reinterpret_cast<uint4*>(&pk[4]);
  }
}

// ---------------------------------------------------------------------------
// Reduce 8 fp16 slice-partials -> fp32 out  [R3 verbatim — validated]
// ---------------------------------------------------------------------------
__global__ void reduce_kernel(const u16* __restrict__ partial, float* __restrict__ out) {
  size_t idx = (size_t)blockIdx.x * 256 + threadIdx.x;
  size_t base = idx * 8;
  float a[8] = {0.f, 0.f, 0.f, 0.f, 0.f, 0.f, 0.f, 0.f};
#pragma unroll
  for (int s = 0; s < NS; ++s) {
    uint4 v = *reinterpret_cast<const uint4*>(partial + (size_t)s * NTOK * HID + base);
    const __fp16* h = (const __fp16*)&v;
#pragma unroll
    for (int e = 0; e < 8; ++e) a[e] += (float)h[e];
  }
  *reinterpret_cast<float4*>(out + base) = make_float4(a[0], a[1], a[2], a[3]);
  *reinterpret_cast<float4*>(out + base + 4) = make_float4(a[4], a[5], a[6], a[7]);
}

extern "C" void kernel_launch(void* const* d_in, const int* in_sizes, int n_in,
                              void* d_out, int out_size, void* d_ws, size_t ws_size,
                              hipStream_t stream) {
  const float* query = (const float*)d_in[0];
  const float* key_  = (const float*)d_in[1];
  const float* value = (const float*)d_in[2];
  const float* Wq = (const float*)d_in[3];
  const float* bq = (const float*)d_in[4];
  const float* Wk = (const float*)d_in[5];
  const float* bk = (const float*)d_in[6];
  const float* Wv = (const float*)d_in[7];
  const float* bv = (const float*)d_in[8];
  float* out = (float*)d_out;

  unsigned char* ws = (unsigned char*)d_ws;
  u16* qws  = (u16*)(ws);                       // 4 MB  [8192][256] bf16
  u16* kws  = (u16*)(ws + (4u << 20));          // 4 MB  [8192][256] bf16
  u16* vtws = (u16*)(ws + (8u << 20));          // 4 MB  [256][8192] bf16
  u16* wcvt = (u16*)(ws + (12u << 20));         // 384 KB  3x[256][256] bf16
  u16* part = (u16*)(ws + (13u << 20));         // 32 MB  8x[8192][256] fp16

  wcvt_kernel<<<192, 256, 0, stream>>>(Wq, Wk, Wv, wcvt);
  proj_kernel<<<384, 256, 0, stream>>>(query, key_, value, wcvt, bq, bk, bv,
                                       qws, kws, vtws);
  attn_kernel<<<512, 256, 0, stream>>>(qws, kws, vtws, part);
  reduce_kernel<<<1024, 256, 0, stream>>>(part, out);
}